// Round 4
// baseline (479.735 us; speedup 1.0000x reference)
//
#include <hip/hip_runtime.h>
#include <math.h>

#define NN 8192
#define NF 128

// ws layout (float indices):
// dinv   [0, 8192)
// c0     [8192, 16384)      zeroed; kFuse accumulates RAW colsums; kTail applies dinv0 + Z-fix
// accum  [16384, 16394)     zeroed (10 used)
// Zcount int at 16394       zeroed
// done   int at 16395       zeroed (kTail last-block ticket)
// (pad to 16416; memset covers [8192, 16416))
// s1p    [16416, 98336)     8192*10 = x@W1, UNSCALED (no dinv)
// acc    [98336, 180256)    8192*10 = raw adj@s1p (pre-dinv0)
// Zlist  ints [180256, 180256+8192)

__device__ __forceinline__ float comp4(const float4& v, int c) {
    return c == 0 ? v.x : c == 1 ? v.y : c == 2 ? v.z : v.w;
}

// ---------------------------------------------------------------------------
// s1p[j,k] = x[j,:] @ W1[:,k]   (NO dinv scaling -> no dependency on degrees)
// ---------------------------------------------------------------------------
__global__ __launch_bounds__(256) void kS1p(const float* __restrict__ x,
                                            const float* __restrict__ W1,
                                            float* __restrict__ s1p) {
    __shared__ float sW[NF * 10];
    for (int i = threadIdx.x; i < NF * 10; i += 256) sW[i] = W1[i];
    __syncthreads();
    int tid = blockIdx.x * 256 + threadIdx.x;   // = j*10 + k, 81920 total
    int j = tid / 10, k = tid % 10;
    const float4* xr = (const float4*)(x + (size_t)j * NF);
    float s = 0.f;
#pragma unroll
    for (int f4 = 0; f4 < 32; f4++) {
        float4 a = xr[f4];
        s += a.x * sW[(f4 * 4 + 0) * 10 + k] + a.y * sW[(f4 * 4 + 1) * 10 + k]
           + a.z * sW[(f4 * 4 + 2) * 10 + k] + a.w * sW[(f4 * 4 + 3) * 10 + k];
    }
    s1p[tid] = s;
}

// ---------------------------------------------------------------------------
// SINGLE pass over adj. Per row i:
//   - EXACT zero count (adj>=0 so zeros == nonpositives) -> dinv[i] final
//     here; suspect rows (cz>0) recorded in Zlist for kTail's correction.
//   - raw column sums (LDS component-major -> conflict-free; flushed by
//     global atomics)
//   - acc[i,k] = sum_j adj[i,j]*s1p[j,k] (raw; dinv0 applied in kTail)
// Exactness: rows with cz==0 have dinv == rsqrtf(8192.f) == dinv0 BITWISE, so
// (adj@s1)[i,k] = dinv0*acc[i,k] + sum_{z in Z}(dinv_z-dinv0)*adj[i,z]*s1p[z,k].
// grid 256 x 512: 8 waves/block (2/SIMD, geometry-capped), 4 rows/wave.
// 3-deep register pipeline: ~900cy HBM latency vs ~800cy of 2-wave compute
// cover at 2-deep -> 3-deep fully covers. ~230 VGPR, capped 256 by (512,2).
// VALU is ~25-30% of the BW-bound iteration time -> exact counting is free.
// ---------------------------------------------------------------------------
__global__ __launch_bounds__(512, 2) void kFuse(const float* __restrict__ adj,
                                                const float* __restrict__ s1p,
                                                float* __restrict__ accO,
                                                float* __restrict__ dinv,
                                                float* __restrict__ c0,
                                                int* __restrict__ Zcount,
                                                int* __restrict__ Zlist) {
    __shared__ float lcs[4][2048];   // component-major colsum: bank = vi%32, conflict-free
    const int t = threadIdx.x;
    const int lane = t & 63, wid = t >> 6;
    for (int n = t; n < 8192; n += 512) ((float*)lcs)[n] = 0.f;
    __syncthreads();

    const int i0 = blockIdx.x * 32 + wid * 4;
    float acc[4][10];
#pragma unroll
    for (int r = 0; r < 4; r++)
#pragma unroll
        for (int k = 0; k < 10; k++) acc[r][k] = 0.f;
    int cz[4] = {0, 0, 0, 0};

    const float4* a0p = (const float4*)(adj + (size_t)(i0 + 0) * NN);
    const float4* a1p = (const float4*)(adj + (size_t)(i0 + 1) * NN);
    const float4* a2p = (const float4*)(adj + (size_t)(i0 + 2) * NN);
    const float4* a3p = (const float4*)(adj + (size_t)(i0 + 3) * NN);
    const float4* spB = (const float4*)s1p;

    auto loadT = [&](float4 (&A)[4], float4 (&S)[10], int v) {
        A[0] = a0p[v]; A[1] = a1p[v]; A[2] = a2p[v]; A[3] = a3p[v];
#pragma unroll
        for (int q = 0; q < 10; q++) S[q] = spB[(size_t)v * 10 + q];
    };

    auto computeT = [&](const float4 (&A)[4], const float4 (&S)[10], int v) {
        // raw column sums: 4 rows pre-summed -> 4 conflict-free LDS atomics
        atomicAdd(&lcs[0][v], A[0].x + A[1].x + A[2].x + A[3].x);
        atomicAdd(&lcs[1][v], A[0].y + A[1].y + A[2].y + A[3].y);
        atomicAdd(&lcs[2][v], A[0].z + A[1].z + A[2].z + A[3].z);
        atomicAdd(&lcs[3][v], A[0].w + A[1].w + A[2].w + A[3].w);
        // exact zero count (adj >= 0: zero <=> nonpositive)
#pragma unroll
        for (int r = 0; r < 4; r++)
            cz[r] += (A[r].x <= 0.f) + (A[r].y <= 0.f) + (A[r].z <= 0.f) + (A[r].w <= 0.f);
        // dot partials; jj-outer so S regs are consumed in load order
#pragma unroll
        for (int jj = 0; jj < 4; jj++) {
            const float a0c = comp4(A[0], jj), a1c = comp4(A[1], jj);
            const float a2c = comp4(A[2], jj), a3c = comp4(A[3], jj);
#pragma unroll
            for (int k = 0; k < 10; k++) {
                const int idx = jj * 10 + k;
                const float s = comp4(S[idx >> 2], idx & 3);
                acc[0][k] = fmaf(a0c, s, acc[0][k]);
                acc[1][k] = fmaf(a1c, s, acc[1][k]);
                acc[2][k] = fmaf(a2c, s, acc[2][k]);
                acc[3][k] = fmaf(a3c, s, acc[3][k]);
            }
        }
    };

    // 3-deep register pipeline over the 32 chunks of 64 float4s
    float4 Aa[4], Ab[4], Ac[4];
    float4 Sa[10], Sb[10], Sc[10];
    int vi = lane;
    loadT(Aa, Sa, vi);
    loadT(Ab, Sb, vi + 64);
#pragma unroll 1
    for (int it = 0; it < 10; it++) {
        loadT(Ac, Sc, vi + 128); computeT(Aa, Sa, vi);
        loadT(Aa, Sa, vi + 192); computeT(Ab, Sb, vi + 64);
        loadT(Ab, Sb, vi + 256); computeT(Ac, Sc, vi + 128);
        vi += 192;
    }
    computeT(Aa, Sa, vi);        // chunk 30
    computeT(Ab, Sb, vi + 64);   // chunk 31

    // wave all-reduce the 40 dot partials + 4 zero counts
#pragma unroll
    for (int r = 0; r < 4; r++) {
#pragma unroll
        for (int k = 0; k < 10; k++)
#pragma unroll
            for (int off = 32; off > 0; off >>= 1)
                acc[r][k] += __shfl_xor(acc[r][k], off, 64);
#pragma unroll
        for (int off = 32; off > 0; off >>= 1)
            cz[r] += __shfl_xor(cz[r], off, 64);
    }

    if (lane == 0) {
#pragma unroll
        for (int r = 0; r < 4; r++) {
            const int i = i0 + r;
            dinv[i] = rsqrtf((float)(NN - cz[r]));   // exact & final
            if (cz[r] != 0) { int p = atomicAdd(Zcount, 1); Zlist[p] = i; }
#pragma unroll
            for (int k = 0; k < 10; k++) accO[i * 10 + k] = acc[r][k];
        }
    }

    __syncthreads();
    // flush block-level raw colsums (256 blocks x 8192 = 2M atomics)
    for (int n = t; n < 8192; n += 512)
        atomicAdd(&c0[n], lcs[n & 3][n >> 2]);
}

// ---------------------------------------------------------------------------
// Tail + finale (h never hits memory; kF2 folded in via last-block ticket):
// thread j:  c_j = dinv0*colsum_j + sum_z (dinv_z-dinv0)*adj[z,j]
//            h_j[k] = relu(dinv_j*(dinv0*acc[j,k] + Zcorr + dinv_j*s1p[j,k]) + b1[k])
//            s2[j,k] = dinv_j*(h_j @ W2[:,k]);  accum[k]+=c_j*s2; accum[5+k]+=dinv_j*s2
// Last block to finish (device-scope ticket) reads accum via atomic RMWs
// (coherent across XCDs) and computes z / z2 / y -> out. No spin-waits:
// every wave terminates unconditionally.
// ---------------------------------------------------------------------------
__global__ __launch_bounds__(256) void kTail(const float* __restrict__ adj,
                                             const float* __restrict__ accI,
                                             const float* __restrict__ s1p,
                                             const float* __restrict__ dinv,
                                             const float* __restrict__ c0,
                                             const int* __restrict__ Zcount,
                                             const int* __restrict__ Zlist,
                                             const float* __restrict__ b1,
                                             const float* __restrict__ W2,
                                             float* __restrict__ accum,
                                             int* __restrict__ done,
                                             const float* __restrict__ b2,
                                             const float* __restrict__ fc1W,
                                             const float* __restrict__ fc1b,
                                             const float* __restrict__ fcW,
                                             const float* __restrict__ fcb,
                                             float* __restrict__ out) {
    const int j = blockIdx.x * 256 + threadIdx.x;
    const float dinv0 = rsqrtf((float)NN);
    const float dj = dinv[j];
    float cj = c0[j] * dinv0;
    float hv[10];
#pragma unroll
    for (int k = 0; k < 10; k++) hv[k] = dinv0 * accI[j * 10 + k];

    const int zc = *Zcount;
    for (int p = 0; p < zc; p++) {
        const int zi = Zlist[p];
        const float dz = dinv[zi] - dinv0;
        cj += dz * adj[(size_t)zi * NN + j];            // coalesced over j
        const float az = dz * adj[(size_t)j * NN + zi]; // strided, |Z| small
#pragma unroll
        for (int k = 0; k < 10; k++) hv[k] += az * s1p[zi * 10 + k];
    }
#pragma unroll
    for (int k = 0; k < 10; k++)
        hv[k] = fmaxf(dj * (hv[k] + dj * s1p[j * 10 + k]) + b1[k], 0.f);

    float p10[10];
#pragma unroll
    for (int k = 0; k < 5; k++) {
        float s = 0.f;
#pragma unroll
        for (int m = 0; m < 10; m++) s += hv[m] * W2[m * 5 + k];
        s *= dj;
        p10[k] = cj * s;
        p10[5 + k] = dj * s;
    }
#pragma unroll
    for (int q = 0; q < 10; q++) {
        float v = p10[q];
#pragma unroll
        for (int off = 32; off > 0; off >>= 1) v += __shfl_xor(v, off, 64);
        if ((threadIdx.x & 63) == 0) atomicAdd(&accum[q], v);
    }

    // ---- finale: last block computes the 7 outputs ----
    __syncthreads();              // barrier drains this block's atomics (vmcnt 0)
    if (threadIdx.x == 0) {
        __threadfence();
        if (atomicAdd(done, 1) == 31) {   // last of the 32 blocks
            float a10[10];
#pragma unroll
            for (int q = 0; q < 10; q++) a10[q] = atomicAdd(&accum[q], 0.f);  // coherent read
            float z[5];
            for (int k = 0; k < 5; k++) {
                float v = (a10[k] + a10[5 + k]) * (1.f / (float)NN) + b2[k];
                z[k] = fmaxf(v, 0.f);
                out[k] = z[k];
            }
            float z2[5];
            for (int m = 0; m < 5; m++) {
                float v = fc1b[m];
                for (int k = 0; k < 5; k++) v += z[k] * fc1W[k * 5 + m];
                z2[m] = fmaxf(v, 0.f);
            }
            for (int n = 0; n < 2; n++) {
                float v = fcb[n];
                for (int m = 0; m < 5; m++) v += z2[m] * fcW[m * 2 + n];
                out[5 + n] = 1.f / (1.f + expf(-v));
            }
        }
    }
}

extern "C" void kernel_launch(void* const* d_in, const int* in_sizes, int n_in,
                              void* d_out, int out_size, void* d_ws, size_t ws_size,
                              hipStream_t stream) {
    const float* x    = (const float*)d_in[0];
    const float* adj  = (const float*)d_in[1];
    const float* W1   = (const float*)d_in[2];
    const float* b1   = (const float*)d_in[3];
    const float* W2   = (const float*)d_in[4];
    const float* b2   = (const float*)d_in[5];
    const float* fc1W = (const float*)d_in[6];
    const float* fc1b = (const float*)d_in[7];
    const float* fcW  = (const float*)d_in[8];
    const float* fcb  = (const float*)d_in[9];
    (void)in_sizes; (void)n_in; (void)out_size; (void)ws_size;

    float* ws    = (float*)d_ws;
    float* dinv  = ws;
    float* c0    = ws + 8192;
    float* accum = ws + 16384;
    int*   Zcount = (int*)(ws + 16394);
    int*   done   = (int*)(ws + 16395);
    float* s1p   = ws + 16416;
    float* acc   = ws + 98336;
    int*   Zlist  = (int*)(ws + 180256);
    float* out = (float*)d_out;

    // single memset covers c0 + accum + Zcount + done (+pad) — ws is poisoned 0xAA
    hipMemsetAsync(c0, 0, (8192 + 32) * sizeof(float), stream);

    kS1p <<<320, 256, 0, stream>>>(x, W1, s1p);
    kFuse<<<256, 512, 0, stream>>>(adj, s1p, acc, dinv, c0, Zcount, Zlist);
    kTail<<<32,  256, 0, stream>>>(adj, acc, s1p, dinv, c0, Zcount, Zlist, b1, W2,
                                   accum, done, b2, fc1W, fc1b, fcW, fcb, out);
}

// Round 5
// 430.540 us; speedup vs baseline: 1.1143x; 1.1143x over previous
//
#include <hip/hip_runtime.h>
#include <math.h>

#define NN 8192
#define NF 128

// ws layout (float indices):
// dinv   [0, 8192)
// c0     [8192, 16384)      zeroed; kFuse accumulates RAW colsums; kTail applies dinv0 + Z-fix
// accum  [16384, 16394)     zeroed (10 used)
// Zcount int at 16394       zeroed
// done   int at 16395       zeroed (kTail last-block ticket)
// (pad to 16416; memset covers [8192, 16416))
// s1p    [16416, 98336)     8192*10 = x@W1, UNSCALED (no dinv)
// acc    [98336, 180256)    8192*10 = raw adj@s1p (pre-dinv0)
// Zlist  ints [180256, 180256+8192)

__device__ __forceinline__ float comp4(const float4& v, int c) {
    return c == 0 ? v.x : c == 1 ? v.y : c == 2 ? v.z : v.w;
}

// ---------------------------------------------------------------------------
// s1p[j,k] = x[j,:] @ W1[:,k]   (NO dinv scaling -> no dependency on degrees)
// ---------------------------------------------------------------------------
__global__ __launch_bounds__(256) void kS1p(const float* __restrict__ x,
                                            const float* __restrict__ W1,
                                            float* __restrict__ s1p) {
    __shared__ float sW[NF * 10];
    for (int i = threadIdx.x; i < NF * 10; i += 256) sW[i] = W1[i];
    __syncthreads();
    int tid = blockIdx.x * 256 + threadIdx.x;   // = j*10 + k, 81920 total
    int j = tid / 10, k = tid % 10;
    const float4* xr = (const float4*)(x + (size_t)j * NF);
    float s = 0.f;
#pragma unroll
    for (int f4 = 0; f4 < 32; f4++) {
        float4 a = xr[f4];
        s += a.x * sW[(f4 * 4 + 0) * 10 + k] + a.y * sW[(f4 * 4 + 1) * 10 + k]
           + a.z * sW[(f4 * 4 + 2) * 10 + k] + a.w * sW[(f4 * 4 + 3) * 10 + k];
    }
    s1p[tid] = s;
}

// ---------------------------------------------------------------------------
// SINGLE pass over adj (R2-proven 2-deep ping-pong; NO launch_bounds
// min-occupancy arg — R4 showed the ",2" hint capped VGPR at 128 and spilled
// ~100 regs -> 148 MB scratch writes, 3.4x slowdown. With 512-thread blocks
// the compiler must fit 1 block/CU anyway (<=256 VGPR), and the ~180 live
// regs of the 2-deep pipeline fit without spill.)
// Per row i:
//   - EXACT zero count (adj>=0: zero <=> nonpositive) -> dinv[i] final here;
//     suspect rows (cz>0) recorded in Zlist for kTail's correction.
//   - raw column sums (LDS component-major -> conflict-free; flushed by
//     global atomics)
//   - acc[i,k] = sum_j adj[i,j]*s1p[j,k] (raw; dinv0 applied in kTail)
// Exactness: rows with cz==0 have dinv == rsqrtf(8192.f) == dinv0 BITWISE, so
// (adj@s1)[i,k] = dinv0*acc[i,k] + sum_{z in Z}(dinv_z-dinv0)*adj[i,z]*s1p[z,k].
// grid 256 x 512: 8 waves/block (2/SIMD), 4 rows/wave.
// ---------------------------------------------------------------------------
__global__ __launch_bounds__(512) void kFuse(const float* __restrict__ adj,
                                             const float* __restrict__ s1p,
                                             float* __restrict__ accO,
                                             float* __restrict__ dinv,
                                             float* __restrict__ c0,
                                             int* __restrict__ Zcount,
                                             int* __restrict__ Zlist) {
    __shared__ float lcs[4][2048];   // component-major colsum: bank = vi%32, conflict-free
    const int t = threadIdx.x;
    const int lane = t & 63, wid = t >> 6;
    for (int n = t; n < 8192; n += 512) ((float*)lcs)[n] = 0.f;
    __syncthreads();

    const int i0 = blockIdx.x * 32 + wid * 4;
    float acc[4][10];
#pragma unroll
    for (int r = 0; r < 4; r++)
#pragma unroll
        for (int k = 0; k < 10; k++) acc[r][k] = 0.f;
    int cz[4] = {0, 0, 0, 0};

    const float4* a0p = (const float4*)(adj + (size_t)(i0 + 0) * NN);
    const float4* a1p = (const float4*)(adj + (size_t)(i0 + 1) * NN);
    const float4* a2p = (const float4*)(adj + (size_t)(i0 + 2) * NN);
    const float4* a3p = (const float4*)(adj + (size_t)(i0 + 3) * NN);
    const float4* spB = (const float4*)s1p;

    auto loadT = [&](float4 (&A)[4], float4 (&S)[10], int v) {
        A[0] = a0p[v]; A[1] = a1p[v]; A[2] = a2p[v]; A[3] = a3p[v];
#pragma unroll
        for (int q = 0; q < 10; q++) S[q] = spB[(size_t)v * 10 + q];
    };

    auto computeT = [&](const float4 (&A)[4], const float4 (&S)[10], int v) {
        // raw column sums: 4 rows pre-summed -> 4 conflict-free LDS atomics
        atomicAdd(&lcs[0][v], A[0].x + A[1].x + A[2].x + A[3].x);
        atomicAdd(&lcs[1][v], A[0].y + A[1].y + A[2].y + A[3].y);
        atomicAdd(&lcs[2][v], A[0].z + A[1].z + A[2].z + A[3].z);
        atomicAdd(&lcs[3][v], A[0].w + A[1].w + A[2].w + A[3].w);
        // exact zero count (adj >= 0: zero <=> nonpositive)
#pragma unroll
        for (int r = 0; r < 4; r++)
            cz[r] += (A[r].x <= 0.f) + (A[r].y <= 0.f) + (A[r].z <= 0.f) + (A[r].w <= 0.f);
        // dot partials; jj-outer so S regs are consumed in load order
#pragma unroll
        for (int jj = 0; jj < 4; jj++) {
            const float a0c = comp4(A[0], jj), a1c = comp4(A[1], jj);
            const float a2c = comp4(A[2], jj), a3c = comp4(A[3], jj);
#pragma unroll
            for (int k = 0; k < 10; k++) {
                const int idx = jj * 10 + k;
                const float s = comp4(S[idx >> 2], idx & 3);
                acc[0][k] = fmaf(a0c, s, acc[0][k]);
                acc[1][k] = fmaf(a1c, s, acc[1][k]);
                acc[2][k] = fmaf(a2c, s, acc[2][k]);
                acc[3][k] = fmaf(a3c, s, acc[3][k]);
            }
        }
    };

    // 2-deep register ping-pong over the 32 chunks of 64 float4s (R2-proven)
    float4 Aa[4], Ba[4];
    float4 Sa[10], Sb[10];
    int vi = lane;
    loadT(Aa, Sa, vi);
#pragma unroll 1
    for (int it = 0; it < 15; it++) {
        loadT(Ba, Sb, vi + 64);
        computeT(Aa, Sa, vi);
        loadT(Aa, Sa, vi + 128);
        computeT(Ba, Sb, vi + 64);
        vi += 128;
    }
    loadT(Ba, Sb, vi + 64);
    computeT(Aa, Sa, vi);
    computeT(Ba, Sb, vi + 64);

    // wave all-reduce the 40 dot partials + 4 zero counts
#pragma unroll
    for (int r = 0; r < 4; r++) {
#pragma unroll
        for (int k = 0; k < 10; k++)
#pragma unroll
            for (int off = 32; off > 0; off >>= 1)
                acc[r][k] += __shfl_xor(acc[r][k], off, 64);
#pragma unroll
        for (int off = 32; off > 0; off >>= 1)
            cz[r] += __shfl_xor(cz[r], off, 64);
    }

    if (lane == 0) {
#pragma unroll
        for (int r = 0; r < 4; r++) {
            const int i = i0 + r;
            dinv[i] = rsqrtf((float)(NN - cz[r]));   // exact & final
            if (cz[r] != 0) { int p = atomicAdd(Zcount, 1); Zlist[p] = i; }
#pragma unroll
            for (int k = 0; k < 10; k++) accO[i * 10 + k] = acc[r][k];
        }
    }

    __syncthreads();
    // flush block-level raw colsums (256 blocks x 8192 = 2M atomics)
    for (int n = t; n < 8192; n += 512)
        atomicAdd(&c0[n], lcs[n & 3][n >> 2]);
}

// ---------------------------------------------------------------------------
// Tail + finale (h never hits memory; kF2 folded in via last-block ticket):
// thread j:  c_j = dinv0*colsum_j + sum_z (dinv_z-dinv0)*adj[z,j]
//            h_j[k] = relu(dinv_j*(dinv0*acc[j,k] + Zcorr + dinv_j*s1p[j,k]) + b1[k])
//            s2[j,k] = dinv_j*(h_j @ W2[:,k]);  accum[k]+=c_j*s2; accum[5+k]+=dinv_j*s2
// Last block to finish (device-scope ticket) reads accum via atomic RMWs
// (coherent across XCDs) and computes z / z2 / y -> out. No spin-waits:
// every wave terminates unconditionally.
// ---------------------------------------------------------------------------
__global__ __launch_bounds__(256) void kTail(const float* __restrict__ adj,
                                             const float* __restrict__ accI,
                                             const float* __restrict__ s1p,
                                             const float* __restrict__ dinv,
                                             const float* __restrict__ c0,
                                             const int* __restrict__ Zcount,
                                             const int* __restrict__ Zlist,
                                             const float* __restrict__ b1,
                                             const float* __restrict__ W2,
                                             float* __restrict__ accum,
                                             int* __restrict__ done,
                                             const float* __restrict__ b2,
                                             const float* __restrict__ fc1W,
                                             const float* __restrict__ fc1b,
                                             const float* __restrict__ fcW,
                                             const float* __restrict__ fcb,
                                             float* __restrict__ out) {
    const int j = blockIdx.x * 256 + threadIdx.x;
    const float dinv0 = rsqrtf((float)NN);
    const float dj = dinv[j];
    float cj = c0[j] * dinv0;
    float hv[10];
#pragma unroll
    for (int k = 0; k < 10; k++) hv[k] = dinv0 * accI[j * 10 + k];

    const int zc = *Zcount;
    for (int p = 0; p < zc; p++) {
        const int zi = Zlist[p];
        const float dz = dinv[zi] - dinv0;
        cj += dz * adj[(size_t)zi * NN + j];            // coalesced over j
        const float az = dz * adj[(size_t)j * NN + zi]; // strided, |Z| small
#pragma unroll
        for (int k = 0; k < 10; k++) hv[k] += az * s1p[zi * 10 + k];
    }
#pragma unroll
    for (int k = 0; k < 10; k++)
        hv[k] = fmaxf(dj * (hv[k] + dj * s1p[j * 10 + k]) + b1[k], 0.f);

    float p10[10];
#pragma unroll
    for (int k = 0; k < 5; k++) {
        float s = 0.f;
#pragma unroll
        for (int m = 0; m < 10; m++) s += hv[m] * W2[m * 5 + k];
        s *= dj;
        p10[k] = cj * s;
        p10[5 + k] = dj * s;
    }
#pragma unroll
    for (int q = 0; q < 10; q++) {
        float v = p10[q];
#pragma unroll
        for (int off = 32; off > 0; off >>= 1) v += __shfl_xor(v, off, 64);
        if ((threadIdx.x & 63) == 0) atomicAdd(&accum[q], v);
    }

    // ---- finale: last block computes the 7 outputs ----
    __syncthreads();              // barrier drains this block's atomics (vmcnt 0)
    if (threadIdx.x == 0) {
        __threadfence();
        if (atomicAdd(done, 1) == 31) {   // last of the 32 blocks
            float a10[10];
#pragma unroll
            for (int q = 0; q < 10; q++) a10[q] = atomicAdd(&accum[q], 0.f);  // coherent read
            float z[5];
            for (int k = 0; k < 5; k++) {
                float v = (a10[k] + a10[5 + k]) * (1.f / (float)NN) + b2[k];
                z[k] = fmaxf(v, 0.f);
                out[k] = z[k];
            }
            float z2[5];
            for (int m = 0; m < 5; m++) {
                float v = fc1b[m];
                for (int k = 0; k < 5; k++) v += z[k] * fc1W[k * 5 + m];
                z2[m] = fmaxf(v, 0.f);
            }
            for (int n = 0; n < 2; n++) {
                float v = fcb[n];
                for (int m = 0; m < 5; m++) v += z2[m] * fcW[m * 2 + n];
                out[5 + n] = 1.f / (1.f + expf(-v));
            }
        }
    }
}

extern "C" void kernel_launch(void* const* d_in, const int* in_sizes, int n_in,
                              void* d_out, int out_size, void* d_ws, size_t ws_size,
                              hipStream_t stream) {
    const float* x    = (const float*)d_in[0];
    const float* adj  = (const float*)d_in[1];
    const float* W1   = (const float*)d_in[2];
    const float* b1   = (const float*)d_in[3];
    const float* W2   = (const float*)d_in[4];
    const float* b2   = (const float*)d_in[5];
    const float* fc1W = (const float*)d_in[6];
    const float* fc1b = (const float*)d_in[7];
    const float* fcW  = (const float*)d_in[8];
    const float* fcb  = (const float*)d_in[9];
    (void)in_sizes; (void)n_in; (void)out_size; (void)ws_size;

    float* ws    = (float*)d_ws;
    float* dinv  = ws;
    float* c0    = ws + 8192;
    float* accum = ws + 16384;
    int*   Zcount = (int*)(ws + 16394);
    int*   done   = (int*)(ws + 16395);
    float* s1p   = ws + 16416;
    float* acc   = ws + 98336;
    int*   Zlist  = (int*)(ws + 180256);
    float* out = (float*)d_out;

    // single memset covers c0 + accum + Zcount + done (+pad) — ws is poisoned 0xAA
    hipMemsetAsync(c0, 0, (8192 + 32) * sizeof(float), stream);

    kS1p <<<320, 256, 0, stream>>>(x, W1, s1p);
    kFuse<<<256, 512, 0, stream>>>(adj, s1p, acc, dinv, c0, Zcount, Zlist);
    kTail<<<32,  256, 0, stream>>>(adj, acc, s1p, dinv, c0, Zcount, Zlist, b1, W2,
                                   accum, done, b2, fc1W, fc1b, fcW, fcb, out);
}